// Round 10
// baseline (317.467 us; speedup 1.0000x reference)
//
#include <hip/hip_runtime.h>
#include <hip/hip_bf16.h>

typedef __attribute__((ext_vector_type(8))) short short8;
typedef __attribute__((ext_vector_type(4))) float f32x4;
typedef __attribute__((ext_vector_type(4))) int int4v;
typedef __attribute__((ext_vector_type(8))) int int8v;

#define DEVFN static __device__ __forceinline__

DEVFN float bf2f(unsigned short u) {
    unsigned int i = ((unsigned int)u) << 16;
    float f; __builtin_memcpy(&f, &i, 4); return f;
}
DEVFN unsigned short f2bf(float f) {
    unsigned int i; __builtin_memcpy(&i, &f, 4);
    unsigned int r = i + 0x7fffu + ((i >> 16) & 1u);
    return (unsigned short)(r >> 16);
}
DEVFN unsigned char f2fp8(float f) {
    int r = __builtin_amdgcn_cvt_pk_fp8_f32(f, f, 0, false);
    return (unsigned char)(r & 0xff);
}
DEVFN float fastrcp(float x) { return __builtin_amdgcn_rcpf(x); }

DEVFN void load_lds16(const void* g, void* l) {
    __builtin_amdgcn_global_load_lds(
        (__attribute__((address_space(1))) void*)g,
        (__attribute__((address_space(3))) void*)l, 16, 0, 0);
}

DEVFN f32x4 mfma_fp8(int8v a, int8v b, f32x4 c) {
    // cbsz=0 (A=fp8 e4m3), blgp=0 (B=fp8 e4m3), scales = 1.0 (e8m0 127)
    return __builtin_amdgcn_mfma_scale_f32_16x16x128_f8f6f4(
        a, b, c, 0, 0, 0, 0x7F7F7F7F, 0, 0x7F7F7F7F);
}

// ---------------- constants ----------------
constexpr int Bsz = 2, T = 2048, C = 1024;
constexpr int NH = 16, NKV = 8, HD = 64;
constexpr int HID = 4096;
constexpr int NTOK = Bsz * T;              // 4096
constexpr size_t MiB = 1024 * 1024;

// workspace offsets (bytes)
constexpr size_t OFF_WQKV = 0;             // bf16 [2048][1024]   4 MiB
constexpr size_t OFF_WOUT = 4 * MiB;       // bf16 [1024][1024]   2 MiB
constexpr size_t OFF_WGATE = 6 * MiB;      // fp8  [4096][1024]   4 MiB (x16)
constexpr size_t OFF_WUP = 10 * MiB;       // fp8  [4096][1024]   4 MiB (x16)
constexpr size_t OFF_WDOWN = 14 * MiB;     // fp8  [1024][4096]   4 MiB (x16)
constexpr size_t OFF_XN1 = 18 * MiB;       // bf16 [4096][1024]   8 MiB
constexpr size_t OFF_P2 = 26 * MiB;        // bf16 2x[4096][1024] 16 MiB
constexpr size_t OFF_QB = 58 * MiB;        // bf16 [2][16][2048][64] 8 MiB
constexpr size_t OFF_KB = 66 * MiB;        // bf16 [2][8][2048][64]  4 MiB
constexpr size_t OFF_VT = 70 * MiB;        // bf16 [2][8][64][2048]  4 MiB
constexpr size_t OFF_CTX = 74 * MiB;       // bf16 [4096][1024]   8 MiB
constexpr size_t OFF_X2 = 82 * MiB;        // f32  [4096][1024]  16 MiB
constexpr size_t OFF_XN2 = 98 * MiB;       // fp8  [4096][1024]   4 MiB (x4)
constexpr size_t OFF_G = 102 * MiB;        // fp8  [4096][4096]  16 MiB (x8)
constexpr size_t OFF_P4 = 118 * MiB;       // bf16 2x[4096][1024] 16 MiB
constexpr size_t OFF_ST = 134 * MiB;       // f32  [2048][32] sin  256 KiB
constexpr size_t OFF_CT = 134 * MiB + 256 * 1024;  // f32 cos     256 KiB
// total ~134.5 MiB

// ---------------- prep: weight cast+transpose + rms1 + rope tables ----------------
// [0,15360): transpose 32x32 tiles (float4 loads, vec stores); [15360,19456): rms rows;
// [19456,19712): rope table
__global__ __launch_bounds__(256) void prep_kernel(
    const float* __restrict__ qk, const float* __restrict__ kk2,
    const float* __restrict__ vk, const float* __restrict__ ok,
    const float* __restrict__ gk, const float* __restrict__ uk,
    const float* __restrict__ dk,
    unsigned short* __restrict__ wqkv, unsigned short* __restrict__ wout,
    unsigned char* __restrict__ wgate, unsigned char* __restrict__ wup,
    unsigned char* __restrict__ wdown,
    const float* __restrict__ x, const float* __restrict__ rms1_scale,
    unsigned short* __restrict__ xn1,
    float* __restrict__ st, float* __restrict__ ct) {
    __shared__ float t[32][33];
    __shared__ float red[4];
    int id = blockIdx.x;
    int tid = threadIdx.x;
    if (id >= 19456) {
        int idx = (id - 19456) * 256 + tid;     // [0, 65536) = t*32 + f
        float fr = (float)(idx & 31) * (1.f / 32.f);
        float freq = powf(1e6f, -fr);
        float a = (float)(idx >> 5) * freq;
        st[idx] = sinf(a);
        ct[idx] = cosf(a);
        return;
    }
    if (id >= 15360) {
        int row = id - 15360;
        const float4 v = *(const float4*)&x[(size_t)row * 1024 + tid * 4];
        float ss = v.x * v.x + v.y * v.y + v.z * v.z + v.w * v.w;
#pragma unroll
        for (int m = 32; m; m >>= 1) ss += __shfl_xor(ss, m, 64);
        if ((tid & 63) == 0) red[tid >> 6] = ss;
        __syncthreads();
        float tot = red[0] + red[1] + red[2] + red[3];
        float inv = rsqrtf(tot * (1.f / 1024.f) + 1e-6f);
        const float4 sc = *(const float4*)&rms1_scale[tid * 4];
        size_t o = (size_t)row * 1024 + tid * 4;
        xn1[o + 0] = f2bf(v.x * inv * (1.f + sc.x));
        xn1[o + 1] = f2bf(v.y * inv * (1.f + sc.y));
        xn1[o + 2] = f2bf(v.z * inv * (1.f + sc.z));
        xn1[o + 3] = f2bf(v.w * inv * (1.f + sc.w));
        return;
    }
    const float* in; int K, N, nx, base; int fp8 = 0;
    unsigned short* out16 = nullptr; unsigned char* out8 = nullptr;
    if (id < 1024)       { in = qk;  out16 = wqkv;                       K = 1024; N = 1024; nx = 32;  base = 0; }
    else if (id < 1536)  { in = kk2; out16 = wqkv + (size_t)1024 * 1024; K = 1024; N = 512;  nx = 16;  base = 1024; }
    else if (id < 2048)  { in = vk;  out16 = wqkv + (size_t)1536 * 1024; K = 1024; N = 512;  nx = 16;  base = 1536; }
    else if (id < 3072)  { in = ok;  out16 = wout;                       K = 1024; N = 1024; nx = 32;  base = 2048; }
    else if (id < 7168)  { in = gk;  out8 = wgate; fp8 = 1;              K = 1024; N = 4096; nx = 128; base = 3072; }
    else if (id < 11264) { in = uk;  out8 = wup; fp8 = 1;                K = 1024; N = 4096; nx = 128; base = 7168; }
    else                 { in = dk;  out8 = wdown; fp8 = 1;              K = 4096; N = 1024; nx = 32;  base = 11264; }
    int lid = id - base;
    int n0 = (lid % nx) * 32, k0 = (lid / nx) * 32;
    // phase 1: float4 coalesced load of the 32x32 tile (1 load/thread)
    {
        int r = tid >> 3, c4 = (tid & 7) * 4;
        const float4 v = *(const float4*)&in[(size_t)(k0 + r) * N + n0 + c4];
        t[r][c4 + 0] = v.x; t[r][c4 + 1] = v.y; t[r][c4 + 2] = v.z; t[r][c4 + 3] = v.w;
    }
    __syncthreads();
    // phase 2: transposed vectorized store (4 elems contiguous along K)
    int nr = tid >> 3, kc4 = (tid & 7) * 4;
    if (fp8) {
        uchar4 o;
        o.x = f2fp8(t[kc4 + 0][nr] * 16.f);
        o.y = f2fp8(t[kc4 + 1][nr] * 16.f);
        o.z = f2fp8(t[kc4 + 2][nr] * 16.f);
        o.w = f2fp8(t[kc4 + 3][nr] * 16.f);
        *(uchar4*)&out8[(size_t)(n0 + nr) * K + k0 + kc4] = o;
    } else {
        ushort4 o;
        o.x = f2bf(t[kc4 + 0][nr]);
        o.y = f2bf(t[kc4 + 1][nr]);
        o.z = f2bf(t[kc4 + 2][nr]);
        o.w = f2bf(t[kc4 + 3][nr]);
        *(ushort4*)&out16[(size_t)(n0 + nr) * K + k0 + kc4] = o;
    }
}

// ---------------- bf16 GEMM (out-proj): C = A @ Bt^T, dbuf counted-vmcnt ----------------
__global__ __launch_bounds__(256) void gemm128(const unsigned short* __restrict__ A,
                                               const unsigned short* __restrict__ Bt,
                                               unsigned short* __restrict__ Cp,
                                               int N, int K, int lda, int ldb,
                                               size_t zA, size_t zB, size_t zC) {
    __shared__ __align__(16) unsigned short As[2][128 * 32];
    __shared__ __align__(16) unsigned short Bs[2][128 * 32];
    A += (size_t)blockIdx.z * zA;
    Bt += (size_t)blockIdx.z * zB;
    const int tid = threadIdx.x;
    const int lane = tid & 63, w = tid >> 6;
    const int quad = lane >> 4, l15 = lane & 15;
    const int wr = w >> 1, wc = w & 1;
    const int m0 = blockIdx.y * 128, n0 = blockIdx.x * 128;

    f32x4 acc[4][4];
#pragma unroll
    for (int i = 0; i < 4; i++)
#pragma unroll
        for (int j = 0; j < 4; j++) acc[i][j] = f32x4{0.f, 0.f, 0.f, 0.f};

    const int stRow = (w << 4) + (lane >> 2);
    const int stCol = (lane & 3) << 3;

    auto STAGE = [&](int kk, int b) {
#pragma unroll
        for (int i = 0; i < 2; i++) {
            load_lds16(A + (size_t)(m0 + (i << 6) + stRow) * lda + kk + stCol,
                       &As[b][((i << 6) + (w << 4)) * 32]);
            load_lds16(Bt + (size_t)(n0 + (i << 6) + stRow) * ldb + kk + stCol,
                       &Bs[b][((i << 6) + (w << 4)) * 32]);
        }
    };

    const int nsteps = K >> 5;
    STAGE(0, 0);
    STAGE(32, 1);
    for (int s = 0; s < nsteps; ++s) {
        if (s < nsteps - 1) asm volatile("s_waitcnt vmcnt(4)\n\ts_barrier" ::: "memory");
        else                asm volatile("s_waitcnt vmcnt(0)\n\ts_barrier" ::: "memory");
        const int b = s & 1;
        short8 a[4], bf[4];
#pragma unroll
        for (int mi = 0; mi < 4; mi++)
            a[mi] = *(const short8*)&As[b][(wr * 64 + mi * 16 + l15) * 32 + quad * 8];
#pragma unroll
        for (int ni = 0; ni < 4; ni++)
            bf[ni] = *(const short8*)&Bs[b][(wc * 64 + ni * 16 + l15) * 32 + quad * 8];
        asm volatile("s_waitcnt lgkmcnt(0)\n\ts_barrier" ::: "memory");
        if (s + 2 < nsteps) STAGE((s + 2) * 32, b);
        __builtin_amdgcn_sched_barrier(0);
        __builtin_amdgcn_s_setprio(1);
#pragma unroll
        for (int mi = 0; mi < 4; mi++)
#pragma unroll
            for (int ni = 0; ni < 4; ni++)
                acc[mi][ni] = __builtin_amdgcn_mfma_f32_16x16x32_bf16(a[mi], bf[ni], acc[mi][ni], 0, 0, 0);
        __builtin_amdgcn_s_setprio(0);
    }
#pragma unroll
    for (int mi = 0; mi < 4; mi++)
#pragma unroll
        for (int ni = 0; ni < 4; ni++)
#pragma unroll
            for (int r = 0; r < 4; r++) {
                int row = m0 + wr * 64 + mi * 16 + quad * 4 + r;
                int col = n0 + wc * 64 + ni * 16 + l15;
                Cp[(size_t)blockIdx.z * zC + (size_t)row * N + col] = f2bf(acc[mi][ni][r]);
            }
}

// ---------------- qkv GEMM with fused RoPE epilogue + fused V transpose ----------------
// cols [0,1024)=q heads 0-15, [1024,1536)=k heads 0-7, [1536,2048)=v.
// RoPE pair (d, d+32) lives in acc[mi][ni] / acc[mi][ni+2] of the same thread.
// V blocks (n0>=1536) transpose through LDS and write vt[head][d][tok] coalesced.
__global__ __launch_bounds__(256) void gemm_qkv(const unsigned short* __restrict__ A,
                                                const unsigned short* __restrict__ Bt,
                                                unsigned short* __restrict__ qb,
                                                unsigned short* __restrict__ kb,
                                                unsigned short* __restrict__ vt,
                                                const float* __restrict__ st,
                                                const float* __restrict__ ct) {
    __shared__ __align__(16) unsigned short As[2][128 * 32];
    __shared__ __align__(16) unsigned short Bs[2][128 * 32];
    __shared__ __align__(16) unsigned short vtile[2][64][136];   // padded: 272B row stride
    const int tid = threadIdx.x;
    const int lane = tid & 63, w = tid >> 6;
    const int quad = lane >> 4, l15 = lane & 15;
    const int wr = w >> 1, wc = w & 1;
    const int m0 = blockIdx.y * 128, n0 = blockIdx.x * 128;

    f32x4 acc[4][4];
#pragma unroll
    for (int i = 0; i < 4; i++)
#pragma unroll
        for (int j = 0; j < 4; j++) acc[i][j] = f32x4{0.f, 0.f, 0.f, 0.f};

    const int stRow = (w << 4) + (lane >> 2);
    const int stCol = (lane & 3) << 3;

    auto STAGE = [&](int kk, int b) {
#pragma unroll
        for (int i = 0; i < 2; i++) {
            load_lds16(A + (size_t)(m0 + (i << 6) + stRow) * 1024 + kk + stCol,
                       &As[b][((i << 6) + (w << 4)) * 32]);
            load_lds16(Bt + (size_t)(n0 + (i << 6) + stRow) * 1024 + kk + stCol,
                       &Bs[b][((i << 6) + (w << 4)) * 32]);
        }
    };

    STAGE(0, 0);
    STAGE(32, 1);
    for (int s = 0; s < 32; ++s) {
        if (s < 31) asm volatile("s_waitcnt vmcnt(4)\n\ts_barrier" ::: "memory");
        else        asm volatile("s_waitcnt vmcnt(0)\n\ts_barrier" ::: "memory");
        const int b = s & 1;
        short8 a[4], bf[4];
#pragma unroll
        for (int mi = 0; mi < 4; mi++)
            a[mi] = *(const short8*)&As[b][(wr * 64 + mi * 16 + l15) * 32 + quad * 8];
#pragma unroll
        for (int ni = 0; ni < 4; ni++)
            bf[ni] = *(const short8*)&Bs[b][(wc * 64 + ni * 16 + l15) * 32 + quad * 8];
        asm volatile("s_waitcnt lgkmcnt(0)\n\ts_barrier" ::: "memory");
        if (s < 30) STAGE((s + 2) * 32, b);
        __builtin_amdgcn_sched_barrier(0);
        __builtin_amdgcn_s_setprio(1);
#pragma unroll
        for (int mi = 0; mi < 4; mi++)
#pragma unroll
            for (int ni = 0; ni < 4; ni++)
                acc[mi][ni] = __builtin_amdgcn_mfma_f32_16x16x32_bf16(a[mi], bf[ni], acc[mi][ni], 0, 0, 0);
        __builtin_amdgcn_s_setprio(0);
    }

    if (n0 < 1536) {
        const int head = (n0 + wc * 64) >> 6;          // 0..23
        const bool isq = head < 16;
        unsigned short* ob = isq ? qb : kb;
        const int hb = isq ? head : head - 16;
        const int hn = isq ? 16 : 8;
#pragma unroll
        for (int ni = 0; ni < 2; ni++) {
            const int d = ni * 16 + l15;               // 0..31
#pragma unroll
            for (int mi = 0; mi < 4; mi++)
#pragma unroll
                for (int r = 0; r < 4; r++) {
                    int row = m0 + wr * 64 + mi * 16 + quad * 4 + r;
                    int t = row & 2047, bb = row >> 11;
                    float c = ct[t * 32 + d], sv = st[t * 32 + d];
                    float x1 = acc[mi][ni][r], x2 = acc[mi][ni + 2][r];
                    size_t obase = ((size_t)(bb * hn + hb) * 2048 + t) * 64;
                    ob[obase + d]      = f2bf(x1 * c - x2 * sv);
                    ob[obase + d + 32] = f2bf(x2 * c + x1 * sv);
                }
        }
    } else {
        // V: deposit transposed tile in LDS ([head][d][tok]), then coalesced write.
        __syncthreads();   // As/Bs reads all done; vtile region is fresh anyway
#pragma unroll
        for (int mi = 0; mi < 4; mi++)
#pragma unroll
            for (int ni = 0; ni < 4; ni++) {
                const int d = ni * 16 + l15;           // 0..63 within head wc
#pragma unroll
                for (int r = 0; r < 4; r++) {
                    int tokloc = wr * 64 + mi * 16 + quad * 4 + r;
                    vtile[wc][d][tokloc] = f2bf(acc[mi][ni][r]);
                }
            }
        __syncthreads();
        const int hvb = (n0 - 1536) >> 6;              // 0,2,4,6
        const int bb = m0 >> 11;
        const int tokbase = m0 & 2047;
#pragma unroll
        for (int it = 0; it < 8; ++it) {
            int c = it * 256 + tid;                    // 0..2047 16B-chunks
            int row = c >> 4;                          // 0..127
            int hh = row >> 6, d = row & 63;
            int tokc = (c & 15) * 8;
            short8 val = *(const short8*)&vtile[hh][d][tokc];
            size_t dst = ((size_t)(bb * 8 + hvb + hh) * 64 + d) * 2048 + tokbase + tokc;
            *(short8*)&vt[dst] = val;
        }
    }
}

// ---------------- fp8 fragment helpers (XOR half-swizzled LDS) ----------------
DEVFN int8v read_frag8(const unsigned char* buf, int rb, int quad) {
    int base = rb * 128;
    int h0 = (2 * quad) ^ (rb & 7);
    int h1 = (2 * quad + 1) ^ (rb & 7);
    int4v lo = *(const int4v*)&buf[base + h0 * 16];
    int4v hi = *(const int4v*)&buf[base + h1 * 16];
    return int8v{lo.x, lo.y, lo.z, lo.w, hi.x, hi.y, hi.z, hi.w};
}

// ---------------- fused gate+up GEMM, fp8 MX K=128: 128M x 128N of BOTH mats ----------------
// R7 geometry (verified correct in R7; perf was killed by allocator spill at
// VGPR_Count=128). Plain __launch_bounds__(256) lets the allocator take ~230
// VGPRs (R2 precedent: 220 no-spill) -> 2 waves/SIMD, 2 blocks/CU, no scratch.
// LDS bytes/FLOP halved vs the 128x64 config; stage(t+1) issues under MFMA(t).
__global__ __launch_bounds__(256) void gateup_kernel(const unsigned char* __restrict__ A,
                                                     const unsigned char* __restrict__ Bg,
                                                     const unsigned char* __restrict__ Bu,
                                                     unsigned char* __restrict__ out) {
    __shared__ __align__(16) unsigned char As[128 * 128];
    __shared__ __align__(16) unsigned char Gs[128 * 128];
    __shared__ __align__(16) unsigned char Us[128 * 128];
    const int tid = threadIdx.x;
    const int lane = tid & 63, w = tid >> 6;
    const int quad = lane >> 4, l15 = lane & 15;
    const int wr = w >> 1, wc = w & 1;
    const int m0 = blockIdx.y * 128, n0 = blockIdx.x * 128;

    f32x4 aG[4][4], aU[4][4];
#pragma unroll
    for (int i = 0; i < 4; i++)
#pragma unroll
        for (int j = 0; j < 4; j++) { aG[i][j] = f32x4{0.f, 0.f, 0.f, 0.f}; aU[i][j] = f32x4{0.f, 0.f, 0.f, 0.f}; }

    const int lrow = lane >> 3;        // row within 8-row issue
    const int hA = (lane & 7) ^ lrow;  // swizzled half

    // stage one K-tile: 12 global_load_lds per thread (A,G,U x 128 rows each)
    auto STAGE = [&](int t) {
#pragma unroll
        for (int j = 0; j < 4; j++) {
            int i = w * 4 + j;
            int r = i * 8 + lrow;
            load_lds16(A  + (size_t)(m0 + r) * 1024 + t * 128 + hA * 16, &As[i * 1024]);
            load_lds16(Bg + (size_t)(n0 + r) * 1024 + t * 128 + hA * 16, &Gs[i * 1024]);
            load_lds16(Bu + (size_t)(n0 + r) * 1024 + t * 128 + hA * 16, &Us[i * 1024]);
        }
    };

    STAGE(0);

#pragma unroll
    for (int t = 0; t < 8; ++t) {
        // stage(t) landed (issued under MFMA(t-1))
        asm volatile("s_waitcnt vmcnt(0)\n\ts_barrier" ::: "memory");
        int8v a[4], bg[4], bu[4];
#pragma unroll
        for (int mi = 0; mi < 4; mi++)
            a[mi] = read_frag8(As, wr * 64 + mi * 16 + l15, quad);
#pragma unroll
        for (int ni = 0; ni < 4; ni++) {
            bg[ni] = read_frag8(Gs, wc * 64 + ni * 16 + l15, quad);
            bu[ni] = read_frag8(Us, wc * 64 + ni * 16 + l15, quad);
        }
        // all waves done reading -> buffers free for tile t+1
        asm volatile("s_waitcnt lgkmcnt(0)\n\ts_barrier" ::: "memory");
        if (t < 7) STAGE(t + 1);
        __builtin_amdgcn_sched_barrier(0);
        __builtin_amdgcn_s_setprio(1);
#pragma unroll
        for (int mi = 0; mi < 4; mi++)
#pragma unroll
            for (int ni = 0; ni < 4; ni++) {
                aG[mi][ni] = mfma_fp8(a[mi], bg[ni], aG[mi][ni]);
                aU[mi][ni] = mfma_fp8(a[mi], bu[ni], aU[mi][ni]);
            }
        __builtin_amdgcn_s_setprio(0);
    }
#pragma unroll
    for (int mi = 0; mi < 4; mi++)
#pragma unroll
        for (int ni = 0; ni < 4; ni++)
#pragma unroll
            for (int r = 0; r < 4; r++) {
                int row = m0 + wr * 64 + mi * 16 + quad * 4 + r;
                int col = n0 + wc * 64 + ni * 16 + l15;
                float vg = aG[mi][ni][r] * (1.f / 64.f);
                float vu = aU[mi][ni][r] * (1.f / 64.f);
                float s = vg * fastrcp(1.f + __expf(-vg));
                out[(size_t)row * 4096 + col] = f2fp8(s * vu * 8.f);
            }
}

// ---------------- down GEMM, fp8 MX K=128, split-K=2, bf16 partials ----------------
__global__ __launch_bounds__(256) void down_gemm(const unsigned char* __restrict__ A,
                                                 const unsigned char* __restrict__ Bt,
                                                 unsigned short* __restrict__ Cp) {
    __shared__ __align__(16) unsigned char As[2][128 * 128];
    __shared__ __align__(16) unsigned char Bs[2][128 * 128];
    const int tid = threadIdx.x;
    const int lane = tid & 63, w = tid >> 6;
    const int quad = lane >> 4, l15 = lane & 15;
    const int wr = w >> 1, wc = w & 1;
    const int m0 = blockIdx.y * 128, n0 = blockIdx.x * 128;
    const int kbase = blockIdx.z * 2048;

    f32x4 acc[4][4];
#pragma unroll
    for (int i = 0; i < 4; i++)
#pragma unroll
        for (int j = 0; j < 4; j++) acc[i][j] = f32x4{0.f, 0.f, 0.f, 0.f};

    const int lrow = lane >> 3;
    const int hA = (lane & 7) ^ lrow;

    auto STAGE = [&](int t, int b) {
#pragma unroll
        for (int j = 0; j < 4; j++) {
            int i = w * 4 + j;
            int r = i * 8 + lrow;
            load_lds16(A + (size_t)(m0 + r) * 4096 + kbase + t * 128 + hA * 16, &As[b][i * 1024]);
            load_lds16(Bt + (size_t)(n0 + r) * 4096 + kbase + t * 128 + hA * 16, &Bs[b][i * 1024]);
        }
    };

    STAGE(0, 0);
    STAGE(1, 1);

#pragma unroll
    for (int t = 0; t < 16; ++t) {
        if (t < 15) asm volatile("s_waitcnt vmcnt(8)\n\ts_barrier" ::: "memory");
        else        asm volatile("s_waitcnt vmcnt(0)\n\ts_barrier" ::: "memory");
        const int b = t & 1;
        int8v a[4], bb[4];
#pragma unroll
        for (int mi = 0; mi < 4; mi++)
            a[mi] = read_frag8(As[b], wr * 64 + mi * 16 + l15, quad);
#pragma unroll
        for (int ni = 0; ni < 4; ni++)
            bb[ni] = read_frag8(Bs[b], wc * 64 + ni * 16 + l15, quad);
        asm volatile("s_waitcnt lgkmcnt(0)\n\ts_barrier" ::: "memory");
        if (t < 14) STAGE(t + 2, b);
        __builtin_amdgcn_sched_barrier(0);
        __builtin_amdgcn_s_setprio(1);
#pragma unroll
        for (int mi = 0; mi < 4; mi++)
#pragma unroll
            for (int ni = 0; ni < 4; ni++)
                acc[mi][ni] = mfma_fp8(a[mi], bb[ni], acc[mi][ni]);
        __builtin_amdgcn_s_setprio(0);
    }
    const size_t Z = (size_t)NTOK * 1024;
#pragma unroll
    for (int mi = 0; mi < 4; mi++)
#pragma unroll
        for (int ni = 0; ni < 4; ni++)
#pragma unroll
            for (int r = 0; r < 4; r++) {
                int row = m0 + wr * 64 + mi * 16 + quad * 4 + r;
                int col = n0 + wc * 64 + ni * 16 + l15;
                Cp[(size_t)blockIdx.z * Z + (size_t)row * 1024 + col] =
                    f2bf(acc[mi][ni][r] * (1.f / 128.f));
            }
}

// ---------------- out-proj reduce: x2 = sum(p[0..1]) + x; xn2 = fp8(rms*4); init outk ----------------
__global__ __launch_bounds__(256) void reduce_out(const unsigned short* __restrict__ p,
                                                  const float* __restrict__ x,
                                                  const float* __restrict__ scale,
                                                  float* __restrict__ x2,
                                                  unsigned char* __restrict__ xn2,
                                                  const float* __restrict__ ksum,
                                                  float* __restrict__ outk) {
    __shared__ float red[4];
    int row = blockIdx.x, tid = threadIdx.x;
    if (row == 0 && tid == 0) outk[0] = ksum[0];
    size_t base = (size_t)row * 1024 + tid * 4;
    const size_t Z = (size_t)NTOK * 1024;
    float4 v = *(const float4*)&x[base];
#pragma unroll
    for (int z = 0; z < 2; z++) {
        ushort4 u = *(const ushort4*)&p[base + z * Z];
        v.x += bf2f(u.x); v.y += bf2f(u.y); v.z += bf2f(u.z); v.w += bf2f(u.w);
    }
    *(float4*)&x2[base] = v;
    float ss = v.x * v.x + v.y * v.y + v.z * v.z + v.w * v.w;
#pragma unroll
    for (int m = 32; m; m >>= 1) ss += __shfl_xor(ss, m, 64);
    if ((tid & 63) == 0) red[tid >> 6] = ss;
    __syncthreads();
    float tot = red[0] + red[1] + red[2] + red[3];
    float inv = rsqrtf(tot * (1.f / 1024.f) + 1e-6f) * 4.f;   // x4 fp8 prescale
    const float4 sc = *(const float4*)&scale[tid * 4];
    xn2[base + 0] = f2fp8(v.x * inv * (1.f + sc.x));
    xn2[base + 1] = f2fp8(v.y * inv * (1.f + sc.y));
    xn2[base + 2] = f2fp8(v.z * inv * (1.f + sc.z));
    xn2[base + 3] = f2fp8(v.w * inv * (1.f + sc.w));
}

// ---------------- down reduce: out = sum(p[0..1]) + x2, fused kurtosis ----------------
__global__ __launch_bounds__(256) void reduce_down(const unsigned short* __restrict__ p,
                                                   const float* __restrict__ x2,
                                                   float* __restrict__ outx,
                                                   float* __restrict__ outk) {
    __shared__ float red[4], r2[4], r4[4];
    int row = blockIdx.x, tid = threadIdx.x;
    size_t base = (size_t)row * 1024 + tid * 4;
    const size_t Z = (size_t)NTOK * 1024;
    float4 v = *(const float4*)&x2[base];
#pragma unroll
    for (int z = 0; z < 2; z++) {
        ushort4 u = *(const ushort4*)&p[base + z * Z];
        v.x += bf2f(u.x); v.y += bf2f(u.y); v.z += bf2f(u.z); v.w += bf2f(u.w);
    }
    *(float4*)&outx[base] = v;
    float s = v.x + v.y + v.z + v.w;
#pragma unroll
    for (int m = 32; m; m >>= 1) s += __shfl_xor(s, m, 64);
    if ((tid & 63) == 0) red[tid >> 6] = s;
    __syncthreads();
    float mean = (red[0] + red[1] + red[2] + red[3]) * (1.f / 1024.f);
    float cx = v.x - mean, cy = v.y - mean, cz = v.z - mean, cw = v.w - mean;
    float x2v = cx * cx, y2 = cy * cy, z2 = cz * cz, w2 = cw * cw;
    float c2 = x2v + y2 + z2 + w2;
    float c4 = x2v * x2v + y2 * y2 + z2 * z2 + w2 * w2;
#pragma unroll
    for (int m = 32; m; m >>= 1) {
        c2 += __shfl_xor(c2, m, 64);
        c4 += __shfl_xor(c4, m, 64);
    }
    if ((tid & 63) == 0) { r2[tid >> 6] = c2; r4[tid >> 6] = c4; }
    __syncthreads();
    if (tid == 0) {
        float m2 = (r2[0] + r2[1] + r2[2] + r2[3]) * (1.f / 1024.f);
        float m4 = (r4[0] + r4[1] + r4[2] + r4[3]) * (1.f / 1024.f);
        float kurt = m4 / (m2 * m2 + 1e-6f) - 3.f;
        if (kurt > 0.f) atomicAdd(outk, kurt);
    }
}

// ---------------- flash attention: K/V double-buffered, counted vmcnt ----------------
__global__ __launch_bounds__(256) void attn_kernel(const unsigned short* __restrict__ qb,
                                                   const unsigned short* __restrict__ kb,
                                                   const unsigned short* __restrict__ vt,
                                                   unsigned short* __restrict__ ctx) {
    __shared__ __align__(16) unsigned short Ks[2][64 * 64];   // [key][dim], swizzled
    __shared__ __align__(16) unsigned short Vs[2][64 * 64];   // [dim][key], swizzled
    __shared__ __align__(16) unsigned short P[4][16 * 64];
    const int tid = threadIdx.x, lane = tid & 63, w = tid >> 6;
    const int quad = lane >> 4, l15 = lane & 15;
    const int qt = blockIdx.x, H = blockIdx.y, b = blockIdx.z;
    const int hkv = H & 7;
    const int qw = qt * 64 + w * 16;

    const unsigned short* qbase = qb + ((size_t)(b * 16 + H) * 2048 + qw) * 64;
    short8 aq0 = *(const short8*)(qbase + (size_t)l15 * 64 + quad * 8);
    short8 aq1 = *(const short8*)(qbase + (size_t)l15 * 64 + 32 + quad * 8);

    const unsigned short* kbase = kb + (size_t)(b * 8 + hkv) * 2048 * 64;
    const unsigned short* vbase = vt + (size_t)(b * 8 + hkv) * 64 * 2048;

    const short bf1 = (short)0x3F80;   // bf16 1.0
    const short8 ones = {bf1, bf1, bf1, bf1, bf1, bf1, bf1, bf1};

    f32x4 O[4];
#pragma unroll
    for (int i = 0; i < 4; i++) O[i] = f32x4{0.f, 0.f, 0.f, 0.f};
    f32x4 lacc = f32x4{0.f, 0.f, 0.f, 0.f};

    const int srow = lane >> 3;                 // 0..7
    const int schunk = (lane & 7) ^ srow;       // logical 16B chunk to fetch
    const int sw = l15 & 7;                     // read-side swizzle

    int kstartB = qt * 64 - 511;
    if (kstartB < 0) kstartB = 0;
    kstartB &= ~63;
    const int nst = (qt * 64 + 63 - kstartB) / 64 + 1;   // 1..9 K-tiles

    auto STAGE = [&](int s, int bb) {
        int k0 = kstartB + s * 64;
#pragma unroll
        for (int rr = 0; rr < 2; rr++) {
            int row = w * 8 + rr * 32 + srow;   // 0..63 across waves+rounds
            load_lds16(kbase + (size_t)(k0 + row) * 64 + schunk * 8,
                       &Ks[bb][(w * 8 + rr * 32) * 64]);
            load_lds16(vbase + (size_t)row * 2048 + k0 + schunk * 8,
                       &Vs[bb][(w * 8 + rr * 32) * 64]);
        }
    };

    STAGE(0, 0);
    if (nst > 1) STAGE(1, 1);

    for (int s = 0; s < nst; ++s) {
        if (s < nst - 1) asm volatile("s_waitcnt vmcnt(4)\n\ts_barrier" ::: "memory");
        else             asm volatile("s_waitcnt vmcnt(0)\n\ts_barrier" ::: "memory");
        const int cur = s & 1;
        const int k0 = kstartB + s * 64;
        f32x4 S[4];
#pragma unroll
        for (int c = 0; c < 4; c++) {
            const unsigned short* kp = &Ks[cur][(c * 16 + l15) * 64];
            short8 kf0 = *(const short8*)&kp[(quad ^ sw) * 8];
            short8 kf1 = *(const short8*)&kp[((4 + quad) ^ sw) * 8];
            f32x4 sa = __builtin_amdgcn_mfma_f32_16x16x32_bf16(aq0, kf0, f32x4{0.f, 0.f, 0.f, 0.f}, 0, 0, 0);
            sa = __builtin_amdgcn_mfma_f32_16x16x32_bf16(aq1, kf1, sa, 0, 0, 0);
            S[c] = sa;
        }
        unsigned short* Pw = P[w];
#pragma unroll
        for (int c = 0; c < 4; c++)
#pragma unroll
            for (int r = 0; r < 4; r++) {
                int i = qw + quad * 4 + r;
                int j = k0 + c * 16 + l15;
                // p = exp(50*tanh(S*0.0025)); tanh via exp + rcp
                float Sc = fminf(3200.f, fmaxf(-3200.f, S[c][r]));
                float e = __expf(Sc * 0.005f);
                float y = 50.f - 100.f * fastrcp(e + 1.f);
                bool ok = (j <= i) && ((i - j) < 512);
                float pv = ok ? __expf(y) : 0.f;
                Pw[(quad * 4 + r) * 64 + c * 16 + l15] = f2bf(pv);
            }
        asm volatile("s_waitcnt lgkmcnt(0)" ::: "memory");
        short8 pf0 = *(const short8*)&Pw[l15 * 64 + quad * 8];
        short8 pf1 = *(const short8*)&Pw[l15 * 64 + 32 + quad * 8];
#pragma unroll
        for (int ni = 0; ni < 4; ni++) {
            const unsigned short* vp = &Vs[cur][(ni * 16 + l15) * 64];
            short8 vf0 = *(const short8*)&vp[(quad ^ sw) * 8];
            short8 vf1 = *(const short8*)&vp[((4 + quad) ^ sw) * 8];
            O[ni] = __builtin_amdgcn_mfma_f32_16x16x32_bf16(pf0, vf0, O[ni], 0, 0, 0);
            O[ni] = __builtin_amdgcn_mfma_f32_16x16x32_bf16(pf1, vf1, O[ni], 0, 0, 0);
        }
        lacc = __builtin_amdgcn_mfma_f32_16x16x32_bf16(pf0, ones, lacc, 0, 0, 0);
        lacc = __builtin_amdgcn_mfma_f32_16x16x32_bf16(pf1, ones, lacc, 0, 0, 0);
        asm volatile("s_waitcnt lgkmcnt(0)\n\ts_barrier" ::: "memory");
        if (s + 2 < nst) STAGE(s + 2, cur);
    }
#pragma unroll
    for (int r = 0; r < 4; r++) {
        float inv = fastrcp(lacc[r]);
        int i = qw + quad * 4 + r;
        size_t tok = (size_t)b * 2048 + i;
#pragma unroll
        for (int ni = 0; ni < 4; ni++)
            ctx[tok * 1024 + H * 64 + ni * 16 + l15] = f2bf(O[ni][r] * inv);
    }
}

// ---------------- launch ----------------
extern "C" void kernel_launch(void* const* d_in, const int* in_sizes, int n_in,
                              void* d_out, int out_size, void* d_ws, size_t ws_size,
                              hipStream_t stream) {
    const float* x = (const float*)d_in[0];
    const float* ksum = (const float*)d_in[1];
    const float* rms1_scale = (const float*)d_in[2];
    const float* q_w = (const float*)d_in[3];
    const float* k_w = (const float*)d_in[4];
    const float* v_w = (const float*)d_in[5];
    const float* out_w = (const float*)d_in[6];
    const float* rms2_scale = (const float*)d_in[7];
    const float* gate_w = (const float*)d_in[8];
    const float* up_w = (const float*)d_in[9];
    const float* down_w = (const float*)d_in[10];

    char* ws = (char*)d_ws;
    unsigned short* wqkv = (unsigned short*)(ws + OFF_WQKV);
    unsigned short* wout = (unsigned short*)(ws + OFF_WOUT);
    unsigned char* wgate = (unsigned char*)(ws + OFF_WGATE);
    unsigned char* wup = (unsigned char*)(ws + OFF_WUP);
    unsigned char* wdown = (unsigned char*)(ws + OFF_WDOWN);
    unsigned short* xn1 = (unsigned short*)(ws + OFF_XN1);
    unsigned short* p2 = (unsigned short*)(ws + OFF_P2);
    unsigned short* qb = (unsigned short*)(ws + OFF_QB);
    unsigned short* kb = (unsigned short*)(ws + OFF_KB);
    unsigned short* vtb = (unsigned short*)(ws + OFF_VT);
    unsigned short* ctx = (unsigned short*)(ws + OFF_CTX);
    float* x2 = (float*)(ws + OFF_X2);
    unsigned char* xn2 = (unsigned char*)(ws + OFF_XN2);
    unsigned char* g = (unsigned char*)(ws + OFF_G);
    unsigned short* p4 = (unsigned short*)(ws + OFF_P4);
    float* st = (float*)(ws + OFF_ST);
    float* ct = (float*)(ws + OFF_CT);
    float* outx = (float*)d_out;
    float* outk = outx + (size_t)NTOK * C;

    // prep: weight transpose+cast + rms1 + rope tables
    prep_kernel<<<19712, 256, 0, stream>>>(
        q_w, k_w, v_w, out_w, gate_w, up_w, down_w,
        wqkv, wout, wgate, wup, wdown, x, rms1_scale, xn1, st, ct);

    // QKV projection with fused RoPE (q/k -> qb/kb) and fused V transpose (-> vt)
    gemm_qkv<<<dim3(2048 / 128, NTOK / 128), 256, 0, stream>>>(
        xn1, wqkv, qb, kb, vtb, st, ct);

    // attention (double-buffered LDS K/V, counted vmcnt)
    attn_kernel<<<dim3(T / 64, NH, Bsz), 256, 0, stream>>>(qb, kb, vtb, ctx);

    // out projection, split-K=2 bf16 partials, then fused residual+rms2(fp8 x4)+kurt init
    gemm128<<<dim3(1024 / 128, NTOK / 128, 2), 256, 0, stream>>>(
        ctx, wout, p2, 1024, 512, 1024, 1024, 512, 512, (size_t)NTOK * 1024);
    reduce_out<<<NTOK, 256, 0, stream>>>(p2, x, rms2_scale, x2, xn2, ksum, outk);

    // fused gate+up fp8 MX -> g = fp8(silu(gate)*up * 8), 128x128 of both mats
    gateup_kernel<<<dim3(HID / 128, NTOK / 128), 256, 0, stream>>>(xn2, wgate, wup, g);

    // down projection fp8 MX, split-K=2 bf16 partials, then fused residual+kurtosis
    down_gemm<<<dim3(1024 / 128, NTOK / 128, 2), 256, 0, stream>>>(g, wdown, p4);
    reduce_down<<<NTOK, 256, 0, stream>>>(p4, x2, outx, outk);

    (void)in_sizes; (void)n_in; (void)out_size; (void)ws_size;
}

// Round 11
// 308.300 us; speedup vs baseline: 1.0297x; 1.0297x over previous
//
#include <hip/hip_runtime.h>
#include <hip/hip_bf16.h>

typedef __attribute__((ext_vector_type(8))) short short8;
typedef __attribute__((ext_vector_type(4))) float f32x4;
typedef __attribute__((ext_vector_type(4))) int int4v;
typedef __attribute__((ext_vector_type(8))) int int8v;

#define DEVFN static __device__ __forceinline__

DEVFN float bf2f(unsigned short u) {
    unsigned int i = ((unsigned int)u) << 16;
    float f; __builtin_memcpy(&f, &i, 4); return f;
}
DEVFN unsigned short f2bf(float f) {
    unsigned int i; __builtin_memcpy(&i, &f, 4);
    unsigned int r = i + 0x7fffu + ((i >> 16) & 1u);
    return (unsigned short)(r >> 16);
}
DEVFN unsigned char f2fp8(float f) {
    int r = __builtin_amdgcn_cvt_pk_fp8_f32(f, f, 0, false);
    return (unsigned char)(r & 0xff);
}
DEVFN float fastrcp(float x) { return __builtin_amdgcn_rcpf(x); }

DEVFN void load_lds16(const void* g, void* l) {
    __builtin_amdgcn_global_load_lds(
        (__attribute__((address_space(1))) void*)g,
        (__attribute__((address_space(3))) void*)l, 16, 0, 0);
}

DEVFN f32x4 mfma_fp8(int8v a, int8v b, f32x4 c) {
    // cbsz=0 (A=fp8 e4m3), blgp=0 (B=fp8 e4m3), scales = 1.0 (e8m0 127)
    return __builtin_amdgcn_mfma_scale_f32_16x16x128_f8f6f4(
        a, b, c, 0, 0, 0, 0x7F7F7F7F, 0, 0x7F7F7F7F);
}

// ---------------- constants ----------------
constexpr int Bsz = 2, T = 2048, C = 1024;
constexpr int NH = 16, NKV = 8, HD = 64;
constexpr int HID = 4096;
constexpr int NTOK = Bsz * T;              // 4096
constexpr size_t MiB = 1024 * 1024;

// workspace offsets (bytes)
constexpr size_t OFF_WQKV = 0;             // bf16 [2048][1024]   4 MiB
constexpr size_t OFF_WOUT = 4 * MiB;       // bf16 [1024][1024]   2 MiB
constexpr size_t OFF_WGATE = 6 * MiB;      // fp8  [4096][1024]   4 MiB (x16)
constexpr size_t OFF_WUP = 10 * MiB;       // fp8  [4096][1024]   4 MiB (x16)
constexpr size_t OFF_WDOWN = 14 * MiB;     // fp8  [1024][4096]   4 MiB (x16)
constexpr size_t OFF_XN1 = 18 * MiB;       // bf16 [4096][1024]   8 MiB
constexpr size_t OFF_P2 = 26 * MiB;        // bf16 2x[4096][1024] 16 MiB
constexpr size_t OFF_QB = 58 * MiB;        // bf16 [2][16][2048][64] 8 MiB
constexpr size_t OFF_KB = 66 * MiB;        // bf16 [2][8][2048][64]  4 MiB
constexpr size_t OFF_VT = 70 * MiB;        // bf16 [2][8][64][2048]  4 MiB
constexpr size_t OFF_CTX = 74 * MiB;       // bf16 [4096][1024]   8 MiB
constexpr size_t OFF_X2 = 82 * MiB;        // f32  [4096][1024]  16 MiB
constexpr size_t OFF_XN2 = 98 * MiB;       // fp8  [4096][1024]   4 MiB (x4)
constexpr size_t OFF_G = 102 * MiB;        // fp8  [4096][4096]  16 MiB (x8)
constexpr size_t OFF_P4 = 118 * MiB;       // bf16 2x[4096][1024] 16 MiB
constexpr size_t OFF_ST = 134 * MiB;       // f32  [2048][32] sin  256 KiB
constexpr size_t OFF_CT = 134 * MiB + 256 * 1024;  // f32 cos     256 KiB
// total ~134.5 MiB

// ---------------- prep: weight cast+transpose + rms1 + rope tables ----------------
// [0,15360): transpose 32x32 tiles (float4 loads, vec stores); [15360,19456): rms rows;
// [19456,19712): rope table
__global__ __launch_bounds__(256) void prep_kernel(
    const float* __restrict__ qk, const float* __restrict__ kk2,
    const float* __restrict__ vk, const float* __restrict__ ok,
    const float* __restrict__ gk, const float* __restrict__ uk,
    const float* __restrict__ dk,
    unsigned short* __restrict__ wqkv, unsigned short* __restrict__ wout,
    unsigned char* __restrict__ wgate, unsigned char* __restrict__ wup,
    unsigned char* __restrict__ wdown,
    const float* __restrict__ x, const float* __restrict__ rms1_scale,
    unsigned short* __restrict__ xn1,
    float* __restrict__ st, float* __restrict__ ct) {
    __shared__ float t[32][33];
    __shared__ float red[4];
    int id = blockIdx.x;
    int tid = threadIdx.x;
    if (id >= 19456) {
        int idx = (id - 19456) * 256 + tid;     // [0, 65536) = t*32 + f
        float fr = (float)(idx & 31) * (1.f / 32.f);
        float freq = powf(1e6f, -fr);
        float a = (float)(idx >> 5) * freq;
        st[idx] = sinf(a);
        ct[idx] = cosf(a);
        return;
    }
    if (id >= 15360) {
        int row = id - 15360;
        const float4 v = *(const float4*)&x[(size_t)row * 1024 + tid * 4];
        float ss = v.x * v.x + v.y * v.y + v.z * v.z + v.w * v.w;
#pragma unroll
        for (int m = 32; m; m >>= 1) ss += __shfl_xor(ss, m, 64);
        if ((tid & 63) == 0) red[tid >> 6] = ss;
        __syncthreads();
        float tot = red[0] + red[1] + red[2] + red[3];
        float inv = rsqrtf(tot * (1.f / 1024.f) + 1e-6f);
        const float4 sc = *(const float4*)&rms1_scale[tid * 4];
        size_t o = (size_t)row * 1024 + tid * 4;
        xn1[o + 0] = f2bf(v.x * inv * (1.f + sc.x));
        xn1[o + 1] = f2bf(v.y * inv * (1.f + sc.y));
        xn1[o + 2] = f2bf(v.z * inv * (1.f + sc.z));
        xn1[o + 3] = f2bf(v.w * inv * (1.f + sc.w));
        return;
    }
    const float* in; int K, N, nx, base; int fp8 = 0;
    unsigned short* out16 = nullptr; unsigned char* out8 = nullptr;
    if (id < 1024)       { in = qk;  out16 = wqkv;                       K = 1024; N = 1024; nx = 32;  base = 0; }
    else if (id < 1536)  { in = kk2; out16 = wqkv + (size_t)1024 * 1024; K = 1024; N = 512;  nx = 16;  base = 1024; }
    else if (id < 2048)  { in = vk;  out16 = wqkv + (size_t)1536 * 1024; K = 1024; N = 512;  nx = 16;  base = 1536; }
    else if (id < 3072)  { in = ok;  out16 = wout;                       K = 1024; N = 1024; nx = 32;  base = 2048; }
    else if (id < 7168)  { in = gk;  out8 = wgate; fp8 = 1;              K = 1024; N = 4096; nx = 128; base = 3072; }
    else if (id < 11264) { in = uk;  out8 = wup; fp8 = 1;                K = 1024; N = 4096; nx = 128; base = 7168; }
    else                 { in = dk;  out8 = wdown; fp8 = 1;              K = 4096; N = 1024; nx = 32;  base = 11264; }
    int lid = id - base;
    int n0 = (lid % nx) * 32, k0 = (lid / nx) * 32;
    // phase 1: float4 coalesced load of the 32x32 tile (1 load/thread)
    {
        int r = tid >> 3, c4 = (tid & 7) * 4;
        const float4 v = *(const float4*)&in[(size_t)(k0 + r) * N + n0 + c4];
        t[r][c4 + 0] = v.x; t[r][c4 + 1] = v.y; t[r][c4 + 2] = v.z; t[r][c4 + 3] = v.w;
    }
    __syncthreads();
    // phase 2: transposed vectorized store (4 elems contiguous along K)
    int nr = tid >> 3, kc4 = (tid & 7) * 4;
    if (fp8) {
        uchar4 o;
        o.x = f2fp8(t[kc4 + 0][nr] * 16.f);
        o.y = f2fp8(t[kc4 + 1][nr] * 16.f);
        o.z = f2fp8(t[kc4 + 2][nr] * 16.f);
        o.w = f2fp8(t[kc4 + 3][nr] * 16.f);
        *(uchar4*)&out8[(size_t)(n0 + nr) * K + k0 + kc4] = o;
    } else {
        ushort4 o;
        o.x = f2bf(t[kc4 + 0][nr]);
        o.y = f2bf(t[kc4 + 1][nr]);
        o.z = f2bf(t[kc4 + 2][nr]);
        o.w = f2bf(t[kc4 + 3][nr]);
        *(ushort4*)&out16[(size_t)(n0 + nr) * K + k0 + kc4] = o;
    }
}

// ---------------- bf16 GEMM (out-proj): C = A @ Bt^T, dbuf counted-vmcnt ----------------
__global__ __launch_bounds__(256) void gemm128(const unsigned short* __restrict__ A,
                                               const unsigned short* __restrict__ Bt,
                                               unsigned short* __restrict__ Cp,
                                               int N, int K, int lda, int ldb,
                                               size_t zA, size_t zB, size_t zC) {
    __shared__ __align__(16) unsigned short As[2][128 * 32];
    __shared__ __align__(16) unsigned short Bs[2][128 * 32];
    A += (size_t)blockIdx.z * zA;
    Bt += (size_t)blockIdx.z * zB;
    const int tid = threadIdx.x;
    const int lane = tid & 63, w = tid >> 6;
    const int quad = lane >> 4, l15 = lane & 15;
    const int wr = w >> 1, wc = w & 1;
    const int m0 = blockIdx.y * 128, n0 = blockIdx.x * 128;

    f32x4 acc[4][4];
#pragma unroll
    for (int i = 0; i < 4; i++)
#pragma unroll
        for (int j = 0; j < 4; j++) acc[i][j] = f32x4{0.f, 0.f, 0.f, 0.f};

    const int stRow = (w << 4) + (lane >> 2);
    const int stCol = (lane & 3) << 3;

    auto STAGE = [&](int kk, int b) {
#pragma unroll
        for (int i = 0; i < 2; i++) {
            load_lds16(A + (size_t)(m0 + (i << 6) + stRow) * lda + kk + stCol,
                       &As[b][((i << 6) + (w << 4)) * 32]);
            load_lds16(Bt + (size_t)(n0 + (i << 6) + stRow) * ldb + kk + stCol,
                       &Bs[b][((i << 6) + (w << 4)) * 32]);
        }
    };

    const int nsteps = K >> 5;
    STAGE(0, 0);
    STAGE(32, 1);
    for (int s = 0; s < nsteps; ++s) {
        if (s < nsteps - 1) asm volatile("s_waitcnt vmcnt(4)\n\ts_barrier" ::: "memory");
        else                asm volatile("s_waitcnt vmcnt(0)\n\ts_barrier" ::: "memory");
        const int b = s & 1;
        short8 a[4], bf[4];
#pragma unroll
        for (int mi = 0; mi < 4; mi++)
            a[mi] = *(const short8*)&As[b][(wr * 64 + mi * 16 + l15) * 32 + quad * 8];
#pragma unroll
        for (int ni = 0; ni < 4; ni++)
            bf[ni] = *(const short8*)&Bs[b][(wc * 64 + ni * 16 + l15) * 32 + quad * 8];
        asm volatile("s_waitcnt lgkmcnt(0)\n\ts_barrier" ::: "memory");
        if (s + 2 < nsteps) STAGE((s + 2) * 32, b);
        __builtin_amdgcn_sched_barrier(0);
        __builtin_amdgcn_s_setprio(1);
#pragma unroll
        for (int mi = 0; mi < 4; mi++)
#pragma unroll
            for (int ni = 0; ni < 4; ni++)
                acc[mi][ni] = __builtin_amdgcn_mfma_f32_16x16x32_bf16(a[mi], bf[ni], acc[mi][ni], 0, 0, 0);
        __builtin_amdgcn_s_setprio(0);
    }
#pragma unroll
    for (int mi = 0; mi < 4; mi++)
#pragma unroll
        for (int ni = 0; ni < 4; ni++)
#pragma unroll
            for (int r = 0; r < 4; r++) {
                int row = m0 + wr * 64 + mi * 16 + quad * 4 + r;
                int col = n0 + wc * 64 + ni * 16 + l15;
                Cp[(size_t)blockIdx.z * zC + (size_t)row * N + col] = f2bf(acc[mi][ni][r]);
            }
}

// ---------------- qkv GEMM with fused RoPE epilogue + fused V transpose ----------------
// cols [0,1024)=q heads 0-15, [1024,1536)=k heads 0-7, [1536,2048)=v.
// RoPE pair (d, d+32) lives in acc[mi][ni] / acc[mi][ni+2] of the same thread.
// V blocks (n0>=1536) transpose through LDS and write vt[head][d][tok] coalesced.
__global__ __launch_bounds__(256) void gemm_qkv(const unsigned short* __restrict__ A,
                                                const unsigned short* __restrict__ Bt,
                                                unsigned short* __restrict__ qb,
                                                unsigned short* __restrict__ kb,
                                                unsigned short* __restrict__ vt,
                                                const float* __restrict__ st,
                                                const float* __restrict__ ct) {
    __shared__ __align__(16) unsigned short As[2][128 * 32];
    __shared__ __align__(16) unsigned short Bs[2][128 * 32];
    __shared__ __align__(16) unsigned short vtile[2][64][136];   // padded: 272B row stride
    const int tid = threadIdx.x;
    const int lane = tid & 63, w = tid >> 6;
    const int quad = lane >> 4, l15 = lane & 15;
    const int wr = w >> 1, wc = w & 1;
    const int m0 = blockIdx.y * 128, n0 = blockIdx.x * 128;

    f32x4 acc[4][4];
#pragma unroll
    for (int i = 0; i < 4; i++)
#pragma unroll
        for (int j = 0; j < 4; j++) acc[i][j] = f32x4{0.f, 0.f, 0.f, 0.f};

    const int stRow = (w << 4) + (lane >> 2);
    const int stCol = (lane & 3) << 3;

    auto STAGE = [&](int kk, int b) {
#pragma unroll
        for (int i = 0; i < 2; i++) {
            load_lds16(A + (size_t)(m0 + (i << 6) + stRow) * 1024 + kk + stCol,
                       &As[b][((i << 6) + (w << 4)) * 32]);
            load_lds16(Bt + (size_t)(n0 + (i << 6) + stRow) * 1024 + kk + stCol,
                       &Bs[b][((i << 6) + (w << 4)) * 32]);
        }
    };

    STAGE(0, 0);
    STAGE(32, 1);
    for (int s = 0; s < 32; ++s) {
        if (s < 31) asm volatile("s_waitcnt vmcnt(4)\n\ts_barrier" ::: "memory");
        else        asm volatile("s_waitcnt vmcnt(0)\n\ts_barrier" ::: "memory");
        const int b = s & 1;
        short8 a[4], bf[4];
#pragma unroll
        for (int mi = 0; mi < 4; mi++)
            a[mi] = *(const short8*)&As[b][(wr * 64 + mi * 16 + l15) * 32 + quad * 8];
#pragma unroll
        for (int ni = 0; ni < 4; ni++)
            bf[ni] = *(const short8*)&Bs[b][(wc * 64 + ni * 16 + l15) * 32 + quad * 8];
        asm volatile("s_waitcnt lgkmcnt(0)\n\ts_barrier" ::: "memory");
        if (s < 30) STAGE((s + 2) * 32, b);
        __builtin_amdgcn_sched_barrier(0);
        __builtin_amdgcn_s_setprio(1);
#pragma unroll
        for (int mi = 0; mi < 4; mi++)
#pragma unroll
            for (int ni = 0; ni < 4; ni++)
                acc[mi][ni] = __builtin_amdgcn_mfma_f32_16x16x32_bf16(a[mi], bf[ni], acc[mi][ni], 0, 0, 0);
        __builtin_amdgcn_s_setprio(0);
    }

    if (n0 < 1536) {
        const int head = (n0 + wc * 64) >> 6;          // 0..23
        const bool isq = head < 16;
        unsigned short* ob = isq ? qb : kb;
        const int hb = isq ? head : head - 16;
        const int hn = isq ? 16 : 8;
#pragma unroll
        for (int ni = 0; ni < 2; ni++) {
            const int d = ni * 16 + l15;               // 0..31
#pragma unroll
            for (int mi = 0; mi < 4; mi++)
#pragma unroll
                for (int r = 0; r < 4; r++) {
                    int row = m0 + wr * 64 + mi * 16 + quad * 4 + r;
                    int t = row & 2047, bb = row >> 11;
                    float c = ct[t * 32 + d], sv = st[t * 32 + d];
                    float x1 = acc[mi][ni][r], x2 = acc[mi][ni + 2][r];
                    size_t obase = ((size_t)(bb * hn + hb) * 2048 + t) * 64;
                    ob[obase + d]      = f2bf(x1 * c - x2 * sv);
                    ob[obase + d + 32] = f2bf(x2 * c + x1 * sv);
                }
        }
    } else {
        // V: deposit transposed tile in LDS ([head][d][tok]), then coalesced write.
        __syncthreads();   // As/Bs reads all done; vtile region is fresh anyway
#pragma unroll
        for (int mi = 0; mi < 4; mi++)
#pragma unroll
            for (int ni = 0; ni < 4; ni++) {
                const int d = ni * 16 + l15;           // 0..63 within head wc
#pragma unroll
                for (int r = 0; r < 4; r++) {
                    int tokloc = wr * 64 + mi * 16 + quad * 4 + r;
                    vtile[wc][d][tokloc] = f2bf(acc[mi][ni][r]);
                }
            }
        __syncthreads();
        const int hvb = (n0 - 1536) >> 6;              // 0,2,4,6
        const int bb = m0 >> 11;
        const int tokbase = m0 & 2047;
#pragma unroll
        for (int it = 0; it < 8; ++it) {
            int c = it * 256 + tid;                    // 0..2047 16B-chunks
            int row = c >> 4;                          // 0..127
            int hh = row >> 6, d = row & 63;
            int tokc = (c & 15) * 8;
            short8 val = *(const short8*)&vtile[hh][d][tokc];
            size_t dst = ((size_t)(bb * 8 + hvb + hh) * 64 + d) * 2048 + tokbase + tokc;
            *(short8*)&vt[dst] = val;
        }
    }
}

// ---------------- fp8 fragment helpers (XOR half-swizzled LDS) ----------------
DEVFN int8v read_frag8(const unsigned char* buf, int rb, int quad) {
    int base = rb * 128;
    int h0 = (2 * quad) ^ (rb & 7);
    int h1 = (2 * quad + 1) ^ (rb & 7);
    int4v lo = *(const int4v*)&buf[base + h0 * 16];
    int4v hi = *(const int4v*)&buf[base + h1 * 16];
    return int8v{lo.x, lo.y, lo.z, lo.w, hi.x, hi.y, hi.z, hi.w};
}

// ---------------- fused gate+up GEMM, fp8 MX K=128: 128x64 tile of both ----------------
// R5 config (best measured, 43 us): double-buffered 64 KiB LDS (2 blocks/CU),
// counted vmcnt (never 0 in steady state), raw s_barrier, setprio around MFMA.
__global__ __launch_bounds__(256) void gateup_kernel(const unsigned char* __restrict__ A,
                                                     const unsigned char* __restrict__ Bg,
                                                     const unsigned char* __restrict__ Bu,
                                                     unsigned char* __restrict__ out) {
    __shared__ __align__(16) unsigned char As[2][128 * 128];
    __shared__ __align__(16) unsigned char Gs[2][64 * 128];
    __shared__ __align__(16) unsigned char Us[2][64 * 128];
    const int tid = threadIdx.x;
    const int lane = tid & 63, w = tid >> 6;
    const int quad = lane >> 4, l15 = lane & 15;
    const int wr = w >> 1, wc = w & 1;
    const int m0 = blockIdx.y * 128, n0 = blockIdx.x * 64;

    f32x4 aG[4][2], aU[4][2];
#pragma unroll
    for (int i = 0; i < 4; i++)
#pragma unroll
        for (int j = 0; j < 2; j++) { aG[i][j] = f32x4{0.f, 0.f, 0.f, 0.f}; aU[i][j] = f32x4{0.f, 0.f, 0.f, 0.f}; }

    const int lrow = lane >> 3;        // row within 8-row issue
    const int hA = (lane & 7) ^ lrow;  // swizzled half

    auto STAGE = [&](int t, int b) {
#pragma unroll
        for (int j = 0; j < 4; j++) {
            int i = w * 4 + j;                 // A: rows 8i..8i+7
            int r = i * 8 + lrow;
            load_lds16(A + (size_t)(m0 + r) * 1024 + t * 128 + hA * 16, &As[b][i * 1024]);
        }
#pragma unroll
        for (int j = 0; j < 2; j++) {
            int i = w * 2 + j;                 // B: rows 8i..8i+7 (64 total)
            int r = i * 8 + lrow;
            load_lds16(Bg + (size_t)(n0 + r) * 1024 + t * 128 + hA * 16, &Gs[b][i * 1024]);
            load_lds16(Bu + (size_t)(n0 + r) * 1024 + t * 128 + hA * 16, &Us[b][i * 1024]);
        }
    };

    STAGE(0, 0);
    STAGE(1, 1);

#pragma unroll
    for (int t = 0; t < 8; ++t) {
        if (t < 7) asm volatile("s_waitcnt vmcnt(8)\n\ts_barrier" ::: "memory");
        else       asm volatile("s_waitcnt vmcnt(0)\n\ts_barrier" ::: "memory");
        const int b = t & 1;
        int8v a[4], bg[2], bu[2];
#pragma unroll
        for (int mi = 0; mi < 4; mi++)
            a[mi] = read_frag8(As[b], wr * 64 + mi * 16 + l15, quad);
#pragma unroll
        for (int ni = 0; ni < 2; ni++) {
            bg[ni] = read_frag8(Gs[b], wc * 32 + ni * 16 + l15, quad);
            bu[ni] = read_frag8(Us[b], wc * 32 + ni * 16 + l15, quad);
        }
        asm volatile("s_waitcnt lgkmcnt(0)\n\ts_barrier" ::: "memory");
        if (t < 6) STAGE(t + 2, b);
        __builtin_amdgcn_sched_barrier(0);
        __builtin_amdgcn_s_setprio(1);
#pragma unroll
        for (int mi = 0; mi < 4; mi++)
#pragma unroll
            for (int ni = 0; ni < 2; ni++) {
                aG[mi][ni] = mfma_fp8(a[mi], bg[ni], aG[mi][ni]);
                aU[mi][ni] = mfma_fp8(a[mi], bu[ni], aU[mi][ni]);
            }
        __builtin_amdgcn_s_setprio(0);
    }
#pragma unroll
    for (int mi = 0; mi < 4; mi++)
#pragma unroll
        for (int ni = 0; ni < 2; ni++)
#pragma unroll
            for (int r = 0; r < 4; r++) {
                int row = m0 + wr * 64 + mi * 16 + quad * 4 + r;
                int col = n0 + wc * 32 + ni * 16 + l15;
                float vg = aG[mi][ni][r] * (1.f / 64.f);
                float vu = aU[mi][ni][r] * (1.f / 64.f);
                float s = vg * fastrcp(1.f + __expf(-vg));
                out[(size_t)row * 4096 + col] = f2fp8(s * vu * 8.f);
            }
}

// ---------------- down GEMM, fp8 MX K=128, split-K=2, bf16 partials ----------------
__global__ __launch_bounds__(256) void down_gemm(const unsigned char* __restrict__ A,
                                                 const unsigned char* __restrict__ Bt,
                                                 unsigned short* __restrict__ Cp) {
    __shared__ __align__(16) unsigned char As[2][128 * 128];
    __shared__ __align__(16) unsigned char Bs[2][128 * 128];
    const int tid = threadIdx.x;
    const int lane = tid & 63, w = tid >> 6;
    const int quad = lane >> 4, l15 = lane & 15;
    const int wr = w >> 1, wc = w & 1;
    const int m0 = blockIdx.y * 128, n0 = blockIdx.x * 128;
    const int kbase = blockIdx.z * 2048;

    f32x4 acc[4][4];
#pragma unroll
    for (int i = 0; i < 4; i++)
#pragma unroll
        for (int j = 0; j < 4; j++) acc[i][j] = f32x4{0.f, 0.f, 0.f, 0.f};

    const int lrow = lane >> 3;
    const int hA = (lane & 7) ^ lrow;

    auto STAGE = [&](int t, int b) {
#pragma unroll
        for (int j = 0; j < 4; j++) {
            int i = w * 4 + j;
            int r = i * 8 + lrow;
            load_lds16(A + (size_t)(m0 + r) * 4096 + kbase + t * 128 + hA * 16, &As[b][i * 1024]);
            load_lds16(Bt + (size_t)(n0 + r) * 4096 + kbase + t * 128 + hA * 16, &Bs[b][i * 1024]);
        }
    };

    STAGE(0, 0);
    STAGE(1, 1);

#pragma unroll
    for (int t = 0; t < 16; ++t) {
        if (t < 15) asm volatile("s_waitcnt vmcnt(8)\n\ts_barrier" ::: "memory");
        else        asm volatile("s_waitcnt vmcnt(0)\n\ts_barrier" ::: "memory");
        const int b = t & 1;
        int8v a[4], bb[4];
#pragma unroll
        for (int mi = 0; mi < 4; mi++)
            a[mi] = read_frag8(As[b], wr * 64 + mi * 16 + l15, quad);
#pragma unroll
        for (int ni = 0; ni < 4; ni++)
            bb[ni] = read_frag8(Bs[b], wc * 64 + ni * 16 + l15, quad);
        asm volatile("s_waitcnt lgkmcnt(0)\n\ts_barrier" ::: "memory");
        if (t < 14) STAGE(t + 2, b);
        __builtin_amdgcn_sched_barrier(0);
        __builtin_amdgcn_s_setprio(1);
#pragma unroll
        for (int mi = 0; mi < 4; mi++)
#pragma unroll
            for (int ni = 0; ni < 4; ni++)
                acc[mi][ni] = mfma_fp8(a[mi], bb[ni], acc[mi][ni]);
        __builtin_amdgcn_s_setprio(0);
    }
    const size_t Z = (size_t)NTOK * 1024;
#pragma unroll
    for (int mi = 0; mi < 4; mi++)
#pragma unroll
        for (int ni = 0; ni < 4; ni++)
#pragma unroll
            for (int r = 0; r < 4; r++) {
                int row = m0 + wr * 64 + mi * 16 + quad * 4 + r;
                int col = n0 + wc * 64 + ni * 16 + l15;
                Cp[(size_t)blockIdx.z * Z + (size_t)row * 1024 + col] =
                    f2bf(acc[mi][ni][r] * (1.f / 128.f));
            }
}

// ---------------- out-proj reduce: x2 = sum(p[0..1]) + x; xn2 = fp8(rms*4); init outk ----------------
__global__ __launch_bounds__(256) void reduce_out(const unsigned short* __restrict__ p,
                                                  const float* __restrict__ x,
                                                  const float* __restrict__ scale,
                                                  float* __restrict__ x2,
                                                  unsigned char* __restrict__ xn2,
                                                  const float* __restrict__ ksum,
                                                  float* __restrict__ outk) {
    __shared__ float red[4];
    int row = blockIdx.x, tid = threadIdx.x;
    if (row == 0 && tid == 0) outk[0] = ksum[0];
    size_t base = (size_t)row * 1024 + tid * 4;
    const size_t Z = (size_t)NTOK * 1024;
    float4 v = *(const float4*)&x[base];
#pragma unroll
    for (int z = 0; z < 2; z++) {
        ushort4 u = *(const ushort4*)&p[base + z * Z];
        v.x += bf2f(u.x); v.y += bf2f(u.y); v.z += bf2f(u.z); v.w += bf2f(u.w);
    }
    *(float4*)&x2[base] = v;
    float ss = v.x * v.x + v.y * v.y + v.z * v.z + v.w * v.w;
#pragma unroll
    for (int m = 32; m; m >>= 1) ss += __shfl_xor(ss, m, 64);
    if ((tid & 63) == 0) red[tid >> 6] = ss;
    __syncthreads();
    float tot = red[0] + red[1] + red[2] + red[3];
    float inv = rsqrtf(tot * (1.f / 1024.f) + 1e-6f) * 4.f;   // x4 fp8 prescale
    const float4 sc = *(const float4*)&scale[tid * 4];
    xn2[base + 0] = f2fp8(v.x * inv * (1.f + sc.x));
    xn2[base + 1] = f2fp8(v.y * inv * (1.f + sc.y));
    xn2[base + 2] = f2fp8(v.z * inv * (1.f + sc.z));
    xn2[base + 3] = f2fp8(v.w * inv * (1.f + sc.w));
}

// ---------------- down reduce: out = sum(p[0..1]) + x2, fused kurtosis ----------------
__global__ __launch_bounds__(256) void reduce_down(const unsigned short* __restrict__ p,
                                                   const float* __restrict__ x2,
                                                   float* __restrict__ outx,
                                                   float* __restrict__ outk) {
    __shared__ float red[4], r2[4], r4[4];
    int row = blockIdx.x, tid = threadIdx.x;
    size_t base = (size_t)row * 1024 + tid * 4;
    const size_t Z = (size_t)NTOK * 1024;
    float4 v = *(const float4*)&x2[base];
#pragma unroll
    for (int z = 0; z < 2; z++) {
        ushort4 u = *(const ushort4*)&p[base + z * Z];
        v.x += bf2f(u.x); v.y += bf2f(u.y); v.z += bf2f(u.z); v.w += bf2f(u.w);
    }
    *(float4*)&outx[base] = v;
    float s = v.x + v.y + v.z + v.w;
#pragma unroll
    for (int m = 32; m; m >>= 1) s += __shfl_xor(s, m, 64);
    if ((tid & 63) == 0) red[tid >> 6] = s;
    __syncthreads();
    float mean = (red[0] + red[1] + red[2] + red[3]) * (1.f / 1024.f);
    float cx = v.x - mean, cy = v.y - mean, cz = v.z - mean, cw = v.w - mean;
    float x2v = cx * cx, y2 = cy * cy, z2 = cz * cz, w2 = cw * cw;
    float c2 = x2v + y2 + z2 + w2;
    float c4 = x2v * x2v + y2 * y2 + z2 * z2 + w2 * w2;
#pragma unroll
    for (int m = 32; m; m >>= 1) {
        c2 += __shfl_xor(c2, m, 64);
        c4 += __shfl_xor(c4, m, 64);
    }
    if ((tid & 63) == 0) { r2[tid >> 6] = c2; r4[tid >> 6] = c4; }
    __syncthreads();
    if (tid == 0) {
        float m2 = (r2[0] + r2[1] + r2[2] + r2[3]) * (1.f / 1024.f);
        float m4 = (r4[0] + r4[1] + r4[2] + r4[3]) * (1.f / 1024.f);
        float kurt = m4 / (m2 * m2 + 1e-6f) - 3.f;
        if (kurt > 0.f) atomicAdd(outk, kurt);
    }
}

// ---------------- flash attention: K/V double-buffered, counted vmcnt ----------------
// R1-style schedule ported from gateup: prologue stages tiles 0/1; per step
// vmcnt(4) (tile t resident, t+1 in flight) -> s_barrier -> compute ->
// lgkmcnt(0)+s_barrier -> STAGE(t+2). P is per-wave (lgkm-ordered), single buffer.
__global__ __launch_bounds__(256) void attn_kernel(const unsigned short* __restrict__ qb,
                                                   const unsigned short* __restrict__ kb,
                                                   const unsigned short* __restrict__ vt,
                                                   unsigned short* __restrict__ ctx) {
    __shared__ __align__(16) unsigned short Ks[2][64 * 64];   // [key][dim], swizzled
    __shared__ __align__(16) unsigned short Vs[2][64 * 64];   // [dim][key], swizzled
    __shared__ __align__(16) unsigned short P[4][16 * 64];
    const int tid = threadIdx.x, lane = tid & 63, w = tid >> 6;
    const int quad = lane >> 4, l15 = lane & 15;
    const int qt = blockIdx.x, H = blockIdx.y, b = blockIdx.z;
    const int hkv = H & 7;
    const int qw = qt * 64 + w * 16;

    const unsigned short* qbase = qb + ((size_t)(b * 16 + H) * 2048 + qw) * 64;
    short8 aq0 = *(const short8*)(qbase + (size_t)l15 * 64 + quad * 8);
    short8 aq1 = *(const short8*)(qbase + (size_t)l15 * 64 + 32 + quad * 8);

    const unsigned short* kbase = kb + (size_t)(b * 8 + hkv) * 2048 * 64;
    const unsigned short* vbase = vt + (size_t)(b * 8 + hkv) * 64 * 2048;

    const short bf1 = (short)0x3F80;   // bf16 1.0
    const short8 ones = {bf1, bf1, bf1, bf1, bf1, bf1, bf1, bf1};

    f32x4 O[4];
#pragma unroll
    for (int i = 0; i < 4; i++) O[i] = f32x4{0.f, 0.f, 0.f, 0.f};
    f32x4 lacc = f32x4{0.f, 0.f, 0.f, 0.f};

    const int srow = lane >> 3;                 // 0..7
    const int schunk = (lane & 7) ^ srow;       // logical 16B chunk to fetch
    const int sw = l15 & 7;                     // read-side swizzle

    int kstartB = qt * 64 - 511;
    if (kstartB < 0) kstartB = 0;
    kstartB &= ~63;
    const int nst = (qt * 64 + 63 - kstartB) / 64 + 1;   // 1..9 K-tiles

    auto STAGE = [&](int s, int bb) {
        int k0 = kstartB + s * 64;
#pragma unroll
        for (int rr = 0; rr < 2; rr++) {
            int row = w * 8 + rr * 32 + srow;   // 0..63 across waves+rounds
            load_lds16(kbase + (size_t)(k0 + row) * 64 + schunk * 8,
                       &Ks[bb][(w * 8 + rr * 32) * 64]);
            load_lds16(vbase + (size_t)row * 2048 + k0 + schunk * 8,
                       &Vs[bb][(w * 8 + rr * 32) * 64]);
        }
    };

    STAGE(0, 0);
    if (nst > 1) STAGE(1, 1);

    for (int s = 0; s < nst; ++s) {
        if (s < nst - 1) asm volatile("s_waitcnt vmcnt(4)\n\ts_barrier" ::: "memory");
        else             asm volatile("s_waitcnt vmcnt(0)\n\ts_barrier" ::: "memory");
        const int cur = s & 1;
        const int k0 = kstartB + s * 64;
        f32x4 S[4];
#pragma unroll
        for (int c = 0; c < 4; c++) {
            const unsigned short* kp = &Ks[cur][(c * 16 + l15) * 64];
            short8 kf0 = *(const short8*)&kp[(quad ^ sw) * 8];
            short8 kf1 = *(const short8*)&kp[((4 + quad) ^ sw) * 8];
            f32x4 sa = __builtin_amdgcn_mfma_f32_16x16x32_bf16(aq0, kf0, f32x4{0.f, 0.f, 0.f, 0.f}, 0, 0, 0);
            sa = __builtin_amdgcn_mfma_f32_16x16x32_bf16(aq1, kf1, sa, 0, 0, 0);
            S[c] = sa;
        }
        unsigned short* Pw = P[w];
#pragma unroll
        for (int c = 0; c < 4; c++)
#pragma unroll
            for (int r = 0; r < 4; r++) {
                int i = qw + quad * 4 + r;
                int j = k0 + c * 16 + l15;
                // p = exp(50*tanh(S*0.0025)); tanh via exp + rcp
                float Sc = fminf(3200.f, fmaxf(-3200.f, S[c][r]));
                float e = __expf(Sc * 0.005f);
                float y = 50.f - 100.f * fastrcp(e + 1.f);
                bool ok = (j <= i) && ((i - j) < 512);
                float pv = ok ? __expf(y) : 0.f;
                Pw[(quad * 4 + r) * 64 + c * 16 + l15] = f2bf(pv);
            }
        asm volatile("s_waitcnt lgkmcnt(0)" ::: "memory");
        short8 pf0 = *(const short8*)&Pw[l15 * 64 + quad * 8];
        short8 pf1 = *(const short8*)&Pw[l15 * 64 + 32 + quad * 8];
#pragma unroll
        for (int ni = 0; ni < 4; ni++) {
            const unsigned short* vp = &Vs[cur][(ni * 16 + l15) * 64];
            short8 vf0 = *(const short8*)&vp[(quad ^ sw) * 8];
            short8 vf1 = *(const short8*)&vp[((4 + quad) ^ sw) * 8];
            O[ni] = __builtin_amdgcn_mfma_f32_16x16x32_bf16(pf0, vf0, O[ni], 0, 0, 0);
            O[ni] = __builtin_amdgcn_mfma_f32_16x16x32_bf16(pf1, vf1, O[ni], 0, 0, 0);
        }
        lacc = __builtin_amdgcn_mfma_f32_16x16x32_bf16(pf0, ones, lacc, 0, 0, 0);
        lacc = __builtin_amdgcn_mfma_f32_16x16x32_bf16(pf1, ones, lacc, 0, 0, 0);
        // all waves done reading buf cur -> safe to overwrite with tile s+2
        asm volatile("s_waitcnt lgkmcnt(0)\n\ts_barrier" ::: "memory");
        if (s + 2 < nst) STAGE(s + 2, cur);
    }
#pragma unroll
    for (int r = 0; r < 4; r++) {
        float inv = fastrcp(lacc[r]);
        int i = qw + quad * 4 + r;
        size_t tok = (size_t)b * 2048 + i;
#pragma unroll
        for (int ni = 0; ni < 4; ni++)
            ctx[tok * 1024 + H * 64 + ni * 16 + l15] = f2bf(O[ni][r] * inv);
    }
}

// ---------------- launch ----------------
extern "C" void kernel_launch(void* const* d_in, const int* in_sizes, int n_in,
                              void* d_out, int out_size, void* d_ws, size_t ws_size,
                              hipStream_t stream) {
    const float* x = (const float*)d_in[0];
    const float* ksum = (const float*)d_in[1];
    const float* rms1_scale = (const float*)d_in[2];
    const float* q_w = (const float*)d_in[3];
    const float* k_w = (const float*)d_in[4];
    const float* v_w = (const float*)d_in[5];
    const float* out_w = (const float*)d_in[6];
    const float* rms2_scale = (const float*)d_in[7];
    const float* gate_w = (const float*)d_in[8];
    const float* up_w = (const float*)d_in[9];
    const float* down_w = (const float*)d_in[10];

    char* ws = (char*)d_ws;
    unsigned short* wqkv = (unsigned short*)(ws + OFF_WQKV);
    unsigned short* wout = (unsigned short*)(ws + OFF_WOUT);
    unsigned char* wgate = (unsigned char*)(ws + OFF_WGATE);
    unsigned char* wup = (unsigned char*)(ws + OFF_WUP);
    unsigned char* wdown = (unsigned char*)(ws + OFF_WDOWN);
    unsigned short* xn1 = (unsigned short*)(ws + OFF_XN1);
    unsigned short* p2 = (unsigned short*)(ws + OFF_P2);
    unsigned short* qb = (unsigned short*)(ws + OFF_QB);
    unsigned short* kb = (unsigned short*)(ws + OFF_KB);
    unsigned short* vtb = (unsigned short*)(ws + OFF_VT);
    unsigned short* ctx = (unsigned short*)(ws + OFF_CTX);
    float* x2 = (float*)(ws + OFF_X2);
    unsigned char* xn2 = (unsigned char*)(ws + OFF_XN2);
    unsigned char* g = (unsigned char*)(ws + OFF_G);
    unsigned short* p4 = (unsigned short*)(ws + OFF_P4);
    float* st = (float*)(ws + OFF_ST);
    float* ct = (float*)(ws + OFF_CT);
    float* outx = (float*)d_out;
    float* outk = outx + (size_t)NTOK * C;

    // prep: weight transpose+cast + rms1 + rope tables
    prep_kernel<<<19712, 256, 0, stream>>>(
        q_w, k_w, v_w, out_w, gate_w, up_w, down_w,
        wqkv, wout, wgate, wup, wdown, x, rms1_scale, xn1, st, ct);

    // QKV projection with fused RoPE (q/k -> qb/kb) and fused V transpose (-> vt)
    gemm_qkv<<<dim3(2048 / 128, NTOK / 128), 256, 0, stream>>>(
        xn1, wqkv, qb, kb, vtb, st, ct);

    // attention (double-buffered LDS K/V, counted vmcnt)
    attn_kernel<<<dim3(T / 64, NH, Bsz), 256, 0, stream>>>(qb, kb, vtb, ctx);

    // out projection, split-K=2 bf16 partials, then fused residual+rms2(fp8 x4)+kurt init
    gemm128<<<dim3(1024 / 128, NTOK / 128, 2), 256, 0, stream>>>(
        ctx, wout, p2, 1024, 512, 1024, 1024, 512, 512, (size_t)NTOK * 1024);
    reduce_out<<<NTOK, 256, 0, stream>>>(p2, x, rms2_scale, x2, xn2, ksum, outk);

    // fused gate+up fp8 MX -> g = fp8(silu(gate)*up * 8)
    gateup_kernel<<<dim3(HID / 64, NTOK / 128), 256, 0, stream>>>(xn2, wgate, wup, g);

    // down projection fp8 MX, split-K=2 bf16 partials, then fused residual+kurtosis
    down_gemm<<<dim3(1024 / 128, NTOK / 128, 2), 256, 0, stream>>>(g, wdown, p4);
    reduce_down<<<NTOK, 256, 0, stream>>>(p4, x2, outx, outk);

    (void)in_sizes; (void)n_in; (void)out_size; (void)ws_size;
}